// Round 5
// baseline (263.894 us; speedup 1.0000x reference)
//
#include <hip/hip_runtime.h>
#include <math.h>

// x [B=512, C=1024, H=8, W=8] f32. out same shape.
#define C_DIM 1024
#define HW 64
#define NT 1024             // threads per block, 16 waves
#define F4B 16384           // C_DIM*HW/4 float4 per batch
#define PER_T 16            // F4B / NT float4 per thread per batch
#define EPSV 1e-8f
#define TINYF 1.17549435e-38f

typedef float f32x4_t __attribute__((ext_vector_type(4)));

// consume a value so the load that produced it cannot be DCE'd (cache warm)
__device__ __forceinline__ void keepf(float v) { asm volatile("" :: "v"(v)); }

__device__ __forceinline__ void threefry2x32_01(unsigned x0, unsigned x1,
                                                unsigned& o0, unsigned& o1) {
    const unsigned ks0 = 0u, ks1 = 1u, ks2 = 0x1BD11BDBu; // 0x1BD11BDA ^ 0 ^ 1
    x0 += ks0; x1 += ks1;
#define TF_R(r) { x0 += x1; x1 = (x1 << (r)) | (x1 >> (32 - (r))); x1 ^= x0; }
    TF_R(13) TF_R(15) TF_R(26) TF_R(6)
    x0 += ks1; x1 += ks2 + 1u;
    TF_R(17) TF_R(29) TF_R(16) TF_R(24)
    x0 += ks2; x1 += ks0 + 2u;
    TF_R(13) TF_R(15) TF_R(26) TF_R(6)
    x0 += ks0; x1 += ks1 + 3u;
    TF_R(17) TF_R(29) TF_R(16) TF_R(24)
    x0 += ks1; x1 += ks2 + 4u;
    TF_R(13) TF_R(15) TF_R(26) TF_R(6)
    x0 += ks2; x1 += ks0 + 5u;
#undef TF_R
    o0 = x0; o1 = x1;
}

// jax_threefry_partitionable=True: counter (hi=0, lo=n), out = o0 ^ o1.
__device__ __forceinline__ unsigned jax_random_bits(unsigned n) {
    unsigned o0, o1;
    threefry2x32_01(0u, n, o0, o1);
    return o0 ^ o1;
}

__device__ __forceinline__ float gumbel01(unsigned n) {
    unsigned bits = jax_random_bits(n);
    float f = __uint_as_float(0x3F800000u | (bits >> 9)) - 1.0f;
    float u = fmaxf(TINYF, f + TINYF);
    return -logf(-logf(u));
}

__device__ __forceinline__ bool bad_val(float v) {
    return ((__float_as_uint(v) & 0x7F800000u) == 0x7F800000u) || (v < 0.0f);
}

// Tiny middle network for one batch: 16 wave partials -> gate[64].
// Runs on wave 0 only (t < 64). sgum = this lane's precomputed gumbel noise.
__device__ __forceinline__ void middle_net(
    int t, float sgum,
    const float4* __restrict__ red,
    const float* __restrict__ w11, const float* __restrict__ w5,
    const float* __restrict__ b5, const float* __restrict__ w6,
    const float* __restrict__ b6,
    float* sm, float* sa16, float* sb16, float* so2, float* shid,
    float* sgate)
{
    // Final reduce across the 16 wave partials: 4 per lane + 2 shuffles.
    {
        int g = t & 15, set = t >> 4;
        float4 a = red[(set * 4 + 0) * 16 + g];
#pragma unroll
        for (int w = 1; w < 4; ++w) {
            float4 o = red[(set * 4 + w) * 16 + g];
            a.x = fmaxf(a.x, o.x); a.y = fmaxf(a.y, o.y);
            a.z = fmaxf(a.z, o.z); a.w = fmaxf(a.w, o.w);
        }
#pragma unroll
        for (int off = 16; off <= 32; off <<= 1) {
            a.x = fmaxf(a.x, __shfl_xor(a.x, off, 64));
            a.y = fmaxf(a.y, __shfl_xor(a.y, off, 64));
            a.z = fmaxf(a.z, __shfl_xor(a.z, off, 64));
            a.w = fmaxf(a.w, __shfl_xor(a.w, off, 64));
        }
        if (t < 16) {
            sm[t * 4 + 0] = a.x; sm[t * 4 + 1] = a.y;
            sm[t * 4 + 2] = a.z; sm[t * 4 + 3] = a.w;
        }
    }
    __builtin_amdgcn_wave_barrier();

    // Windows: categorical (precomputed gumbel) + max + mean pooling.
    // One (window, j) pair per lane; 4-lane shfl argmax, first-max tie-break.
    {
        int w = t >> 2, j = t & 3;
        int hh = 2 * (w >> 2) + (j >> 1), ww = 2 * (w & 3) + (j & 1);
        float v = sm[hh * 8 + ww];
        float wc = bad_val(v) ? EPSV : v;
        float s = wc + sgum;
        int bi = j;
        float bwc = wc;
        float mx = v;
        float ssum = v;
#pragma unroll
        for (int m = 1; m <= 2; m <<= 1) {
            float s2   = __shfl_xor(s, m, 64);
            int   bi2  = __shfl_xor(bi, m, 64);
            float bwc2 = __shfl_xor(bwc, m, 64);
            float mx2  = __shfl_xor(mx, m, 64);
            float ss2  = __shfl_xor(ssum, m, 64);
            bool take = (s2 > s) || (s2 == s && bi2 < bi);
            if (take) { s = s2; bi = bi2; bwc = bwc2; }
            mx = fmaxf(mx, mx2);
            ssum += ss2;
        }
        if (j == 0) sa16[w] = 0.1f * bwc + 0.6f * mx + 0.3f * (ssum * 0.25f);
    }
    __builtin_amdgcn_wave_barrier();

    // 3x3 conv (1->1, SAME, no bias) on 4x4. Lanes 0..15.
    if (t < 16) {
        int i = t >> 2, j = t & 3;
        float acc = 0.0f;
#pragma unroll
        for (int dy = -1; dy <= 1; ++dy) {
            int yy = i + dy;
            if (yy < 0 || yy > 3) continue;
#pragma unroll
            for (int dx = -1; dx <= 1; ++dx) {
                int xx = j + dx;
                if (xx < 0 || xx > 3) continue;
                acc += sa16[yy * 4 + xx] * w11[(dy + 1) * 3 + (dx + 1)];
            }
        }
        sb16[t] = acc;
    }
    __builtin_amdgcn_wave_barrier();

    // Bilinear resize 4x4 -> 8x8 (align_corners=False). All 64 lanes.
    {
        int y = t >> 3, xx2 = t & 7;
        float sy = (y + 0.5f) * 0.5f - 0.5f;
        float sx = (xx2 + 0.5f) * 0.5f - 0.5f;
        float fy = fminf(fmaxf(sy, 0.0f), 3.0f);
        float fx = fminf(fmaxf(sx, 0.0f), 3.0f);
        int iy0 = (int)floorf(fy); int iy1 = min(iy0 + 1, 3); float ry = fy - (float)iy0;
        int ix0 = (int)floorf(fx); int ix1 = min(ix0 + 1, 3); float rx = fx - (float)ix0;
        float v00 = sb16[iy0 * 4 + ix0], v01 = sb16[iy0 * 4 + ix1];
        float v10 = sb16[iy1 * 4 + ix0], v11 = sb16[iy1 * 4 + ix1];
        float top = v00 * (1.0f - rx) + v01 * rx;
        float bot = v10 * (1.0f - rx) + v11 * rx;
        so2[t] = top * (1.0f - ry) + bot * ry;
    }
    __builtin_amdgcn_wave_barrier();

    // conv5: [2->4] 3x3 SAME + bias + relu on 8x8 (ch0 = m, ch1 = out2).
    {
        int y = t >> 3, x2 = t & 7;
        float a0 = b5[0], a1 = b5[1], a2 = b5[2], a3 = b5[3];
#pragma unroll
        for (int dy = -1; dy <= 1; ++dy) {
            int yy = y + dy;
            if (yy < 0 || yy > 7) continue;
#pragma unroll
            for (int dx = -1; dx <= 1; ++dx) {
                int xx = x2 + dx;
                if (xx < 0 || xx > 7) continue;
                float i0 = sm[yy * 8 + xx];
                float i1 = so2[yy * 8 + xx];
                int kk = (dy + 1) * 3 + (dx + 1);
                a0 += i0 * w5[0 * 18 + kk] + i1 * w5[0 * 18 + 9 + kk];
                a1 += i0 * w5[1 * 18 + kk] + i1 * w5[1 * 18 + 9 + kk];
                a2 += i0 * w5[2 * 18 + kk] + i1 * w5[2 * 18 + 9 + kk];
                a3 += i0 * w5[3 * 18 + kk] + i1 * w5[3 * 18 + 9 + kk];
            }
        }
        shid[0 * 64 + t] = fmaxf(a0, 0.0f);
        shid[1 * 64 + t] = fmaxf(a1, 0.0f);
        shid[2 * 64 + t] = fmaxf(a2, 0.0f);
        shid[3 * 64 + t] = fmaxf(a3, 0.0f);
    }
    __builtin_amdgcn_wave_barrier();

    // conv6: [4->1] 3x3 SAME + bias + sigmoid -> gate (LDS).
    {
        int y = t >> 3, x2 = t & 7;
        float acc = b6[0];
#pragma unroll
        for (int dy = -1; dy <= 1; ++dy) {
            int yy = y + dy;
            if (yy < 0 || yy > 7) continue;
#pragma unroll
            for (int dx = -1; dx <= 1; ++dx) {
                int xx = x2 + dx;
                if (xx < 0 || xx > 7) continue;
                int kk = (dy + 1) * 3 + (dx + 1);
                int p = yy * 8 + xx;
                acc += shid[0 * 64 + p] * w6[0 + kk]
                     + shid[1 * 64 + p] * w6[9 + kk]
                     + shid[2 * 64 + p] * w6[18 + kk]
                     + shid[3 * 64 + p] * w6[27 + kk];
            }
        }
        sgate[t] = 1.0f / (1.0f + expf(-acc));
    }
}

// ---------------- 2-batch software-pipelined fused kernel -------------------
// Grid = B/2 blocks x 1024 threads; block handles batches b0=bid, b1=bid+B/2.
// S1: stream-max b0 (gumbel + weight prefetch under load latency).
// S2: stream-max b1; wave0 overlaps middle(b0) with its own outstanding loads.
// S3: all apply b0 (re-read from L2/IC); wave0 first computes middle(b1).
// S4: all apply b1. Both middles hide under streaming; 3 block barriers total.
__global__ __launch_bounds__(NT) void sa_fused_kernel(
    const float* __restrict__ x,
    const float* __restrict__ w11,
    const float* __restrict__ w5,
    const float* __restrict__ b5,
    const float* __restrict__ w6,
    const float* __restrict__ b6,
    float* __restrict__ out)
{
    const int bid = blockIdx.x;
    const int t = threadIdx.x;
    const int half = gridDim.x;            // B/2
    const int b0 = bid, b1 = bid + half;
    const int wv = t >> 6, lane = t & 63;

    const float4* __restrict__ x4 = (const float4*)x;
    const float4* __restrict__ xb0 = x4 + (size_t)b0 * F4B;
    const float4* __restrict__ xb1 = x4 + (size_t)b1 * F4B;
    float4* __restrict__ ob0 = (float4*)out + (size_t)b0 * F4B;
    float4* __restrict__ ob1 = (float4*)out + (size_t)b1 * F4B;

    __shared__ float4 red0[16 * 16];
    __shared__ float4 red1[16 * 16];
    __shared__ float sm[64], sa16[16], sb16[16], so2[64], shid[4 * 64];
    __shared__ __align__(16) float sgate0[64];
    __shared__ __align__(16) float sgate1[64];

    // ---- S1: stream x[b0]; gumbel + weight prefetch overlap load latency ---
    float4 xv[PER_T];
#pragma unroll
    for (int i = 0; i < PER_T; ++i) xv[i] = xb0[t + NT * i];
    if (t == 0) {  // warm L1/L2 cachelines the middle phases will hit
        keepf(w11[0]); keepf(w5[0]); keepf(w5[32]); keepf(w5[64]);
        keepf(b5[0]);  keepf(w6[0]); keepf(w6[32]); keepf(b6[0]);
    }
    const float sgum0 = gumbel01((unsigned)(b0 * 64 + lane));
    float4 pm = make_float4(-INFINITY, -INFINITY, -INFINITY, -INFINITY);
#pragma unroll
    for (int i = 0; i < PER_T; ++i) {
        pm.x = fmaxf(pm.x, xv[i].x); pm.y = fmaxf(pm.y, xv[i].y);
        pm.z = fmaxf(pm.z, xv[i].z); pm.w = fmaxf(pm.w, xv[i].w);
    }
#pragma unroll
    for (int off = 16; off <= 32; off <<= 1) {
        pm.x = fmaxf(pm.x, __shfl_xor(pm.x, off, 64));
        pm.y = fmaxf(pm.y, __shfl_xor(pm.y, off, 64));
        pm.z = fmaxf(pm.z, __shfl_xor(pm.z, off, 64));
        pm.w = fmaxf(pm.w, __shfl_xor(pm.w, off, 64));
    }
    if (lane < 16) red0[wv * 16 + lane] = pm;
    __syncthreads();

    // ---- S2: stream x[b1]; wave0 middle(b0) under its outstanding loads ----
    float4 yv[PER_T];
#pragma unroll
    for (int i = 0; i < PER_T; ++i) yv[i] = xb1[t + NT * i];
    const float sgum1 = gumbel01((unsigned)(b1 * 64 + lane));
    if (t < 64)
        middle_net(t, sgum0, red0, w11, w5, b5, w6, b6,
                   sm, sa16, sb16, so2, shid, sgate0);
    pm = make_float4(-INFINITY, -INFINITY, -INFINITY, -INFINITY);
#pragma unroll
    for (int i = 0; i < PER_T; ++i) {
        pm.x = fmaxf(pm.x, yv[i].x); pm.y = fmaxf(pm.y, yv[i].y);
        pm.z = fmaxf(pm.z, yv[i].z); pm.w = fmaxf(pm.w, yv[i].w);
    }
#pragma unroll
    for (int off = 16; off <= 32; off <<= 1) {
        pm.x = fmaxf(pm.x, __shfl_xor(pm.x, off, 64));
        pm.y = fmaxf(pm.y, __shfl_xor(pm.y, off, 64));
        pm.z = fmaxf(pm.z, __shfl_xor(pm.z, off, 64));
        pm.w = fmaxf(pm.w, __shfl_xor(pm.w, off, 64));
    }
    if (lane < 16) red1[wv * 16 + lane] = pm;
    __syncthreads();

    // ---- S3: wave0 middle(b1); all apply b0 from L2/IC; nt stores ----------
    if (t < 64)
        middle_net(t, sgum1, red1, w11, w5, b5, w6, b6,
                   sm, sa16, sb16, so2, shid, sgate1);
    {
        const float4 g0 = ((const float4*)sgate0)[t & 15];
#pragma unroll
        for (int i = 0; i < PER_T; ++i) {
            float4 v = xb0[t + NT * i];
            f32x4_t o;
            o.x = fmaxf(v.x * g0.x, 0.0f);
            o.y = fmaxf(v.y * g0.y, 0.0f);
            o.z = fmaxf(v.z * g0.z, 0.0f);
            o.w = fmaxf(v.w * g0.w, 0.0f);
            __builtin_nontemporal_store(o, (f32x4_t*)&ob0[t + NT * i]);
        }
    }
    __syncthreads();

    // ---- S4: all apply b1 --------------------------------------------------
    {
        const float4 g1 = ((const float4*)sgate1)[t & 15];
#pragma unroll
        for (int i = 0; i < PER_T; ++i) {
            float4 v = xb1[t + NT * i];
            f32x4_t o;
            o.x = fmaxf(v.x * g1.x, 0.0f);
            o.y = fmaxf(v.y * g1.y, 0.0f);
            o.z = fmaxf(v.z * g1.z, 0.0f);
            o.w = fmaxf(v.w * g1.w, 0.0f);
            __builtin_nontemporal_store(o, (f32x4_t*)&ob1[t + NT * i]);
        }
    }
}

extern "C" void kernel_launch(void* const* d_in, const int* in_sizes, int n_in,
                              void* d_out, int out_size, void* d_ws, size_t ws_size,
                              hipStream_t stream) {
    const float* x   = (const float*)d_in[0];
    const float* w11 = (const float*)d_in[1];
    const float* w5  = (const float*)d_in[2];
    const float* b5  = (const float*)d_in[3];
    const float* w6  = (const float*)d_in[4];
    const float* b6  = (const float*)d_in[5];
    float* out  = (float*)d_out;

    int B = in_sizes[0] / (C_DIM * HW);  // 512
    sa_fused_kernel<<<dim3(B / 2), dim3(NT), 0, stream>>>(x, w11, w5, b5, w6, b6, out);
}

// Round 6
// 262.377 us; speedup vs baseline: 1.0058x; 1.0058x over previous
//
#include <hip/hip_runtime.h>
#include <math.h>

// x [B=512, C=1024, H=8, W=8] f32. out same shape.
#define C_DIM 1024
#define HW 64
#define F4B 16384           // C_DIM*HW/4 float4 per batch
#define EPSV 1e-8f
#define TINYF 1.17549435e-38f

typedef float f32x4_t __attribute__((ext_vector_type(4)));

__device__ __forceinline__ void threefry2x32_01(unsigned x0, unsigned x1,
                                                unsigned& o0, unsigned& o1) {
    const unsigned ks0 = 0u, ks1 = 1u, ks2 = 0x1BD11BDBu; // 0x1BD11BDA ^ 0 ^ 1
    x0 += ks0; x1 += ks1;
#define TF_R(r) { x0 += x1; x1 = (x1 << (r)) | (x1 >> (32 - (r))); x1 ^= x0; }
    TF_R(13) TF_R(15) TF_R(26) TF_R(6)
    x0 += ks1; x1 += ks2 + 1u;
    TF_R(17) TF_R(29) TF_R(16) TF_R(24)
    x0 += ks2; x1 += ks0 + 2u;
    TF_R(13) TF_R(15) TF_R(26) TF_R(6)
    x0 += ks0; x1 += ks1 + 3u;
    TF_R(17) TF_R(29) TF_R(16) TF_R(24)
    x0 += ks1; x1 += ks2 + 4u;
    TF_R(13) TF_R(15) TF_R(26) TF_R(6)
    x0 += ks2; x1 += ks0 + 5u;
#undef TF_R
    o0 = x0; o1 = x1;
}

// jax_threefry_partitionable=True: counter (hi=0, lo=n), out = o0 ^ o1.
__device__ __forceinline__ unsigned jax_random_bits(unsigned n) {
    unsigned o0, o1;
    threefry2x32_01(0u, n, o0, o1);
    return o0 ^ o1;
}

__device__ __forceinline__ float gumbel01(unsigned n) {
    unsigned bits = jax_random_bits(n);
    float f = __uint_as_float(0x3F800000u | (bits >> 9)) - 1.0f;
    float u = fmaxf(TINYF, f + TINYF);
    return -logf(-logf(u));
}

__device__ __forceinline__ bool bad_val(float v) {
    return ((__float_as_uint(v) & 0x7F800000u) == 0x7F800000u) || (v < 0.0f);
}

// ---------- Kernel A: quarter-batch partial channel max -> ws partials ------
// Grid B*4 x 256. Block (b,q) reads a contiguous 64 KB quarter of batch b
// (256 channels x 64 hw) and writes partial max[64] to part[b][q][hw].
// 256-thread blocks lift the 64-VGPR cap -> deep load pipeline (the r4 limiter).
__global__ __launch_bounds__(256) void sa_maxpart_kernel(
    const float* __restrict__ x,
    float* __restrict__ part)
{
    const int bid = blockIdx.x;
    const int t = threadIdx.x;
    const int b = bid >> 2, q = bid & 3;

    const float4* __restrict__ xq =
        (const float4*)x + (size_t)b * F4B + (size_t)q * 4096;

    // Thread t covers f4 idx t + 256*i -> hw4 group g = t & 15 fixed.
    float4 pm = make_float4(-INFINITY, -INFINITY, -INFINITY, -INFINITY);
#pragma unroll
    for (int i = 0; i < 16; ++i) {
        float4 v = xq[t + 256 * i];
        pm.x = fmaxf(pm.x, v.x); pm.y = fmaxf(pm.y, v.y);
        pm.z = fmaxf(pm.z, v.z); pm.w = fmaxf(pm.w, v.w);
    }
    // Reduce the 4 c-slices within this wave (lanes xor 16, 32).
#pragma unroll
    for (int off = 16; off <= 32; off <<= 1) {
        pm.x = fmaxf(pm.x, __shfl_xor(pm.x, off, 64));
        pm.y = fmaxf(pm.y, __shfl_xor(pm.y, off, 64));
        pm.z = fmaxf(pm.z, __shfl_xor(pm.z, off, 64));
        pm.w = fmaxf(pm.w, __shfl_xor(pm.w, off, 64));
    }
    __shared__ float4 red[4 * 16];
    const int wv = t >> 6, lane = t & 63;
    if (lane < 16) red[wv * 16 + lane] = pm;
    __syncthreads();
    if (t < 16) {
        float4 a = red[t];
#pragma unroll
        for (int w = 1; w < 4; ++w) {
            float4 o = red[w * 16 + t];
            a.x = fmaxf(a.x, o.x); a.y = fmaxf(a.y, o.y);
            a.z = fmaxf(a.z, o.z); a.w = fmaxf(a.w, o.w);
        }
        // hw = g*4 + j for group g = t
        float* dst = part + ((size_t)b * 4 + q) * 64 + t * 4;
        dst[0] = a.x; dst[1] = a.y; dst[2] = a.z; dst[3] = a.w;
    }
}

// ---------- Kernel M: middle network per batch -> gate[B][64] in ws ---------
// Grid B x 64 (one wave per batch). 512 independent tiny blocks give the
// scheduler full phase diversity; no fat-block serialization.
__global__ __launch_bounds__(64) void sa_middle_kernel(
    const float* __restrict__ part,
    const float* __restrict__ w11,
    const float* __restrict__ w5,
    const float* __restrict__ b5,
    const float* __restrict__ w6,
    const float* __restrict__ b6,
    float* __restrict__ gate)
{
    const int b = blockIdx.x;
    const int t = threadIdx.x;  // 0..63 == hw

    __shared__ float sm[64], sa16[16], sb16[16], so2[64], shid[4 * 64];

    // Combine the 4 quarter partials.
    const float* pb = part + (size_t)b * 256;
    float m = fmaxf(fmaxf(pb[t], pb[64 + t]), fmaxf(pb[128 + t], pb[192 + t]));
    sm[t] = m;
    const float sgum = gumbel01((unsigned)(b * 64 + t));
    __builtin_amdgcn_wave_barrier();

    // Windows: categorical (gumbel) + max + mean pooling.
    // One (window, j) pair per lane; 4-lane shfl argmax, first-max tie-break.
    {
        int w = t >> 2, j = t & 3;
        int hh = 2 * (w >> 2) + (j >> 1), ww = 2 * (w & 3) + (j & 1);
        float v = sm[hh * 8 + ww];
        float wc = bad_val(v) ? EPSV : v;
        float s = wc + sgum;
        int bi = j;
        float bwc = wc;
        float mx = v;
        float ssum = v;
#pragma unroll
        for (int mk = 1; mk <= 2; mk <<= 1) {
            float s2   = __shfl_xor(s, mk, 64);
            int   bi2  = __shfl_xor(bi, mk, 64);
            float bwc2 = __shfl_xor(bwc, mk, 64);
            float mx2  = __shfl_xor(mx, mk, 64);
            float ss2  = __shfl_xor(ssum, mk, 64);
            bool take = (s2 > s) || (s2 == s && bi2 < bi);
            if (take) { s = s2; bi = bi2; bwc = bwc2; }
            mx = fmaxf(mx, mx2);
            ssum += ss2;
        }
        if (j == 0) sa16[w] = 0.1f * bwc + 0.6f * mx + 0.3f * (ssum * 0.25f);
    }
    __builtin_amdgcn_wave_barrier();

    // 3x3 conv (1->1, SAME, no bias) on 4x4. Lanes 0..15.
    if (t < 16) {
        int i = t >> 2, j = t & 3;
        float acc = 0.0f;
#pragma unroll
        for (int dy = -1; dy <= 1; ++dy) {
            int yy = i + dy;
            if (yy < 0 || yy > 3) continue;
#pragma unroll
            for (int dx = -1; dx <= 1; ++dx) {
                int xx = j + dx;
                if (xx < 0 || xx > 3) continue;
                acc += sa16[yy * 4 + xx] * w11[(dy + 1) * 3 + (dx + 1)];
            }
        }
        sb16[t] = acc;
    }
    __builtin_amdgcn_wave_barrier();

    // Bilinear resize 4x4 -> 8x8 (align_corners=False).
    {
        int y = t >> 3, xx2 = t & 7;
        float sy = (y + 0.5f) * 0.5f - 0.5f;
        float sx = (xx2 + 0.5f) * 0.5f - 0.5f;
        float fy = fminf(fmaxf(sy, 0.0f), 3.0f);
        float fx = fminf(fmaxf(sx, 0.0f), 3.0f);
        int iy0 = (int)floorf(fy); int iy1 = min(iy0 + 1, 3); float ry = fy - (float)iy0;
        int ix0 = (int)floorf(fx); int ix1 = min(ix0 + 1, 3); float rx = fx - (float)ix0;
        float v00 = sb16[iy0 * 4 + ix0], v01 = sb16[iy0 * 4 + ix1];
        float v10 = sb16[iy1 * 4 + ix0], v11 = sb16[iy1 * 4 + ix1];
        float top = v00 * (1.0f - rx) + v01 * rx;
        float bot = v10 * (1.0f - rx) + v11 * rx;
        so2[t] = top * (1.0f - ry) + bot * ry;
    }
    __builtin_amdgcn_wave_barrier();

    // conv5: [2->4] 3x3 SAME + bias + relu on 8x8 (ch0 = m, ch1 = out2).
    {
        int y = t >> 3, x2 = t & 7;
        float a0 = b5[0], a1 = b5[1], a2 = b5[2], a3 = b5[3];
#pragma unroll
        for (int dy = -1; dy <= 1; ++dy) {
            int yy = y + dy;
            if (yy < 0 || yy > 7) continue;
#pragma unroll
            for (int dx = -1; dx <= 1; ++dx) {
                int xx = x2 + dx;
                if (xx < 0 || xx > 7) continue;
                float i0 = sm[yy * 8 + xx];
                float i1 = so2[yy * 8 + xx];
                int kk = (dy + 1) * 3 + (dx + 1);
                a0 += i0 * w5[0 * 18 + kk] + i1 * w5[0 * 18 + 9 + kk];
                a1 += i0 * w5[1 * 18 + kk] + i1 * w5[1 * 18 + 9 + kk];
                a2 += i0 * w5[2 * 18 + kk] + i1 * w5[2 * 18 + 9 + kk];
                a3 += i0 * w5[3 * 18 + kk] + i1 * w5[3 * 18 + 9 + kk];
            }
        }
        shid[0 * 64 + t] = fmaxf(a0, 0.0f);
        shid[1 * 64 + t] = fmaxf(a1, 0.0f);
        shid[2 * 64 + t] = fmaxf(a2, 0.0f);
        shid[3 * 64 + t] = fmaxf(a3, 0.0f);
    }
    __builtin_amdgcn_wave_barrier();

    // conv6: [4->1] 3x3 SAME + bias + sigmoid -> gate (ws).
    {
        int y = t >> 3, x2 = t & 7;
        float acc = b6[0];
#pragma unroll
        for (int dy = -1; dy <= 1; ++dy) {
            int yy = y + dy;
            if (yy < 0 || yy > 7) continue;
#pragma unroll
            for (int dx = -1; dx <= 1; ++dx) {
                int xx = x2 + dx;
                if (xx < 0 || xx > 7) continue;
                int kk = (dy + 1) * 3 + (dx + 1);
                int p = yy * 8 + xx;
                acc += shid[0 * 64 + p] * w6[0 + kk]
                     + shid[1 * 64 + p] * w6[9 + kk]
                     + shid[2 * 64 + p] * w6[18 + kk]
                     + shid[3 * 64 + p] * w6[27 + kk];
            }
        }
        gate[(size_t)b * 64 + t] = 1.0f / (1.0f + expf(-acc));
    }
}

// ---------- Kernel B: out = relu(x * gate), pure stream ---------------------
// Grid B*4 x 256, fill-kernel-shaped. x re-read hits LLC (warmed by A);
// nt stores keep out from evicting x.
__global__ __launch_bounds__(256) void sa_apply_kernel(
    const float* __restrict__ x,
    const float* __restrict__ gate,
    float* __restrict__ out)
{
    const int bid = blockIdx.x;
    const int t = threadIdx.x;
    const int b = bid >> 2;
    const size_t base = (size_t)bid * 4096;  // float4 units

    const float4* __restrict__ x4 = (const float4*)x;
    float4* __restrict__ o4 = (float4*)out;

    const float4 gv = ((const float4*)(gate + (size_t)b * 64))[t & 15];

#pragma unroll
    for (int i = 0; i < 16; ++i) {
        size_t idx = base + t + 256 * i;
        float4 v = x4[idx];
        f32x4_t o;
        o.x = fmaxf(v.x * gv.x, 0.0f);
        o.y = fmaxf(v.y * gv.y, 0.0f);
        o.z = fmaxf(v.z * gv.z, 0.0f);
        o.w = fmaxf(v.w * gv.w, 0.0f);
        __builtin_nontemporal_store(o, (f32x4_t*)&o4[idx]);
    }
}

extern "C" void kernel_launch(void* const* d_in, const int* in_sizes, int n_in,
                              void* d_out, int out_size, void* d_ws, size_t ws_size,
                              hipStream_t stream) {
    const float* x   = (const float*)d_in[0];
    const float* w11 = (const float*)d_in[1];
    const float* w5  = (const float*)d_in[2];
    const float* b5  = (const float*)d_in[3];
    const float* w6  = (const float*)d_in[4];
    const float* b6  = (const float*)d_in[5];
    float* out  = (float*)d_out;

    int B = in_sizes[0] / (C_DIM * HW);  // 512
    float* gate = (float*)d_ws;                    // B*64 floats   = 128 KB
    float* part = (float*)d_ws + (size_t)B * 64;   // B*4*64 floats = 512 KB

    sa_maxpart_kernel<<<dim3(B * 4), dim3(256), 0, stream>>>(x, part);
    sa_middle_kernel<<<dim3(B), dim3(64), 0, stream>>>(part, w11, w5, b5, w6, b6, gate);
    sa_apply_kernel<<<dim3(B * 4), dim3(256), 0, stream>>>(x, gate, out);
}